// Round 14
// baseline (204.209 us; speedup 1.0000x reference)
//
#include <hip/hip_runtime.h>
#include <hip/hip_fp16.h>
#include <math.h>

#define NPROJ 96
#define NANG  96
#define DET   192
#define NPIX  16384            // 128*128
#define SLICE (NANG*DET)       // 18432

// DSD/DU = DSD/DV = 1000/3.5
#define KPROJ 285.7142857142857f

__device__ __forceinline__ float frcp(float x) { return __builtin_amdgcn_rcpf(x); }

__device__ __forceinline__ float ffract(float x) {
#if __has_builtin(__builtin_amdgcn_fractf)
    return __builtin_amdgcn_fractf(x);
#else
    return x - floorf(x);
#endif
}

typedef __fp16 h2 __attribute__((ext_vector_type(2)));

__device__ __forceinline__ unsigned pack2(float a, float b) {
    h2 p = __builtin_amdgcn_cvt_pkrtz(a, b);
    return __builtin_bit_cast(unsigned, p);
}
__device__ __forceinline__ h2 as_h2(unsigned u) { return __builtin_bit_cast(h2, u); }

#if __has_builtin(__builtin_amdgcn_fdot2)
#define FDOT2(a, b, c) __builtin_amdgcn_fdot2((a), (b), (c), false)
#else
__device__ __forceinline__ float FDOT2(h2 a, h2 b, float c) {
    return c + (float)a[0] * (float)b[0] + (float)a[1] * (float)b[1];
}
#endif

// ---------------------------------------------------------------------------
// K1a: deriv -> OVERLAPPING uint2: derivq[row][d] = (pr(d), pr(d+1)),
// pr(d) = half2(g[d], g[d+1]). One dwordx2 covers both x-pair pixels' taps.
// (correctness-proven in r11)
// ---------------------------------------------------------------------------
__global__ __launch_bounds__(192) void k_deriv2(const float* __restrict__ sino,
                                                const float* __restrict__ wgt,
                                                uint2* __restrict__ derivq) {
    __shared__ float row[DET];
    const int r = blockIdx.x;          // p*96 + a
    const int d = threadIdx.x;         // 0..191
    const int base = r * DET + d;
    row[d] = sino[base] * wgt[base];
    __syncthreads();
    auto grad = [&](int i) -> float {
        i = (i > DET-1) ? DET-1 : i;
        if (i == 0)       return row[1] - row[0];
        if (i == DET-1)   return row[DET-1] - row[DET-2];
        return 0.5f * (row[i+1] - row[i-1]);
    };
    const float g0 = grad(d), g1 = grad(d+1), g2 = grad(d+2);
    derivq[base] = make_uint2(pack2(g0, g1), pack2(g1, g2));
}

// K1b: fallback pair layout (dword per d).
__global__ __launch_bounds__(192) void k_deriv(const float* __restrict__ sino,
                                               const float* __restrict__ wgt,
                                               unsigned* __restrict__ derivp) {
    __shared__ float row[DET];
    const int r = blockIdx.x;
    const int d = threadIdx.x;
    const int base = r * DET + d;
    row[d] = sino[base] * wgt[base];
    __syncthreads();
    auto grad = [&](int i) -> float {
        i = (i > DET-1) ? DET-1 : i;
        if (i == 0)       return row[1] - row[0];
        if (i == DET-1)   return row[DET-1] - row[DET-2];
        return 0.5f * (row[i+1] - row[i-1]);
    };
    derivp[base] = pack2(grad(d), grad(d+1));
}

// ---------------------------------------------------------------------------
// Shared bp2d epilogue writing the every-v QUAD layout (r13 winner):
//   wq[p][v][u] = uint4( pr(v,u), pr(v+1,u), pr(v+2,u), pr(v+3,u) )
// pr of row v lands in slot k of quad v-k, k=0..3.
// ---------------------------------------------------------------------------
__device__ __forceinline__ void epi_quad(const float* buf, int tid, int pixbase,
                                         int p, unsigned* wq_dw) {
    unsigned* sq = wq_dw + p * (NPIX * 4);
    #pragma unroll
    for (int i = 0; i < 2; ++i) {
        const int l   = 2*tid + i;
        const int pix = pixbase + l;
        const int u   = pix & 127;
        const int v   = pix >> 7;
        const float v0 = buf[l];
        const float v1 = (u < 127) ? buf[l + 1] : 0.0f;   // u=127 pair unused
        const unsigned pr = pack2(v0, v1);
        #pragma unroll
        for (int k = 0; k < 4; ++k) {
            const int vb = v - k;
            if (vb >= 0) sq[(((vb << 7) + u) << 2) + k] = pr;
        }
    }
}

// ---------------------------------------------------------------------------
// K2a: 2D backprojection, x-PAIR SHARED loads (r11-proven loop): thread
// handles 2 x-adjacent pixels; |pos1-pos0| = |cos| <= 1 so both pair-taps
// come from ONE dwordx2 of derivq -> 96 loads/thread (was 192).
// grid (96 p, 32 chunks), block 256. No masks.
// ---------------------------------------------------------------------------
__global__ __launch_bounds__(256) void k_bp2d_pair(const uint2* __restrict__ derivq,
                                                   unsigned* __restrict__ wq_dw) {
    __shared__ float sc[NANG], ss[NANG];
    __shared__ float buf[512];
    const int p   = blockIdx.x;
    const int tid = threadIdx.x;

    if (tid < NANG) {
        float s_, c_;
        sincosf((float)tid * (float)(3.14159265358979323846 / 96.0), &s_, &c_);
        sc[tid] = c_; ss[tid] = s_;
    }

    const int pixbase = blockIdx.y * 512;
    const int px0 = pixbase + 2*tid;       // even x
    const float fx0 = (float)(px0 & 127) - 63.5f;
    const float fy  = (float)(px0 >> 7)  - 63.5f;
    float acc0 = 0.0f, acc1 = 0.0f;
    __syncthreads();   // trig ready

    const uint2* rowq = derivq + p * SLICE;
    for (int a = 0; a < NANG; ++a, rowq += DET) {
        const float cb = sc[a], sb = ss[a];
        const float pos0 = fmaf(cb, fx0, fmaf(sb, fy, 95.5f));
        const float pos1 = pos0 + cb;
        const int i0 = (int)pos0;
        const int i1 = (int)pos1;
        const int m  = (i0 < i1) ? i0 : i1;
        const uint2 q = rowq[m];           // (pr(m), pr(m+1)), 8B aligned
        const unsigned pa = (i0 == m) ? q.x : q.y;
        const unsigned pb = (i1 == m) ? q.x : q.y;
        const float f0 = ffract(pos0);
        const float f1 = ffract(pos1);
        acc0 = FDOT2(as_h2(pa), as_h2(pack2(1.0f - f0, f0)), acc0);
        acc1 = FDOT2(as_h2(pb), as_h2(pack2(1.0f - f1, f1)), acc1);
    }

    const float fx1 = fx0 + 1.0f;
    buf[2*tid]     = acc0 * (1000.0f * rsqrtf(1000000.0f + fx0*fx0 + fy*fy));
    buf[2*tid + 1] = acc1 * (1000.0f * rsqrtf(1000000.0f + fx1*fx1 + fy*fy));
    __syncthreads();
    epi_quad(buf, tid, pixbase, p, wq_dw);
}

// K2b: fallback — per-pixel dword loads from pair-layout derivp (r13 form).
__global__ __launch_bounds__(256) void k_bp2d_fb(const unsigned* __restrict__ derivp,
                                                 unsigned* __restrict__ wq_dw) {
    __shared__ float sc[NANG], ss[NANG];
    __shared__ float buf[512];
    const int p   = blockIdx.x;
    const int tid = threadIdx.x;
    if (tid < NANG) {
        float s_, c_;
        sincosf((float)tid * (float)(3.14159265358979323846 / 96.0), &s_, &c_);
        sc[tid] = c_; ss[tid] = s_;
    }
    const int pixbase = blockIdx.y * 512;
    const int px0 = pixbase + 2*tid;
    const float fx0 = (float)(px0 & 127) - 63.5f;
    const float fy  = (float)(px0 >> 7)  - 63.5f;
    float acc0 = 0.0f, acc1 = 0.0f;
    __syncthreads();
    const unsigned* rowp = derivp + p * SLICE;
    for (int a = 0; a < NANG; ++a, rowp += DET) {
        const float cb = sc[a], sb = ss[a];
        const float pos0 = fmaf(cb, fx0, fmaf(sb, fy, 95.5f));
        const float pos1 = pos0 + cb;
        const int i0 = (int)pos0;
        const int i1 = (int)pos1;
        const float f0 = ffract(pos0);
        const float f1 = ffract(pos1);
        acc0 = FDOT2(as_h2(rowp[i0]), as_h2(pack2(1.0f - f0, f0)), acc0);
        acc1 = FDOT2(as_h2(rowp[i1]), as_h2(pack2(1.0f - f1, f1)), acc1);
    }
    const float fx1 = fx0 + 1.0f;
    buf[2*tid]     = acc0 * (1000.0f * rsqrtf(1000000.0f + fx0*fx0 + fy*fy));
    buf[2*tid + 1] = acc1 * (1000.0f * rsqrtf(1000000.0f + fx1*fx1 + fy*fy));
    __syncthreads();
    epi_quad(buf, tid, pixbase, p, wq_dw);
}

// ---------------------------------------------------------------------------
// K3: 3D cone-beam backprojection + PReLU — r13 WINNER, unchanged:
// every-v quad loads, ONE dwordx4 per z-pair, w2 folded into u-weights.
// grid (64 y-pairs, 32 z-chunks) = 2048 blocks = 32 waves/CU.
// pu in [11,116], pv in [19,108] -> no masks.
// ---------------------------------------------------------------------------
__global__ __launch_bounds__(256) void k_bp3d_q(const uint4* __restrict__ wq,
                                                const float* __restrict__ prelu,
                                                float* __restrict__ out) {
    __shared__ float sc[NPROJ], ss[NPROJ];
    const int tid = threadIdx.x;
    const int x   = tid & 127;
    const int y   = (blockIdx.x << 1) | (tid >> 7);
    const int z0  = blockIdx.y << 2;

    if (tid < NPROJ) {
        float s_, c_;
        sincosf((float)tid * (float)(2.0 * 3.14159265358979323846 / 96.0), &s_, &c_);
        sc[tid] = c_; ss[tid] = s_;
    }

    const float fx  = (float)x - 63.5f;
    const float fy  = (float)y - 63.5f;
    const float zlo = (float)z0 - 63.5f;

    float acc[4];
    #pragma unroll
    for (int j = 0; j < 4; ++j) acc[j] = 0.0f;

    __syncthreads();   // trig ready — the only barrier

    const uint4* bb = wq;                // per-beta slice = 128*128 uint4
    for (int b = 0; b < NPROJ; ++b, bb += NPIX) {
        const float cb    = sc[b], sb = ss[b];
        const float t     = fmaf(fx, cb,  fy * sb);
        const float sdist = fmaf(fy, cb, -fx * sb);
        const float invr  = frcp(500.0f + t);
        const float pu    = fmaf(KPROJ * sdist, invr, 63.5f);
        const int   iu0   = (int)pu;             // pu in [11, 116]
        const float fu    = ffract(pu);
        float w2 = 1000.0f * invr; w2 *= w2;
        const float Kz    = KPROJ * invr;
        const h2    wuw   = as_h2(pack2((1.0f - fu) * w2, fu * w2));

        #pragma unroll
        for (int pr2 = 0; pr2 < 2; ++pr2) {      // z-pairs (0,1), (2,3)
            const float pvA = fmaf(Kz, zlo + (float)(2*pr2), 63.5f);
            const float pvB = pvA + Kz;
            const int   ivA = (int)pvA;          // pv in [19, 108]
            const int   ivB = (int)pvB;          // ivA or ivA+1
            const float fvA = ffract(pvA);
            const float fvB = ffract(pvB);
            const uint4 q   = bb[(ivA << 7) + iu0];   // rows ivA..ivA+3
            const int   d   = ivB - ivA;              // 0 or 1
            const float tA  = FDOT2(as_h2(q.x), wuw, 0.0f);
            const float bA  = FDOT2(as_h2(q.y), wuw, 0.0f);
            acc[2*pr2]     += fmaf(fvA, bA - tA, tA);
            const unsigned tBv = d ? q.y : q.x;
            const unsigned bBv = d ? q.z : q.y;
            const float tB  = FDOT2(as_h2(tBv), wuw, 0.0f);
            const float bB  = FDOT2(as_h2(bBv), wuw, 0.0f);
            acc[2*pr2 + 1] += fmaf(fvB, bB - tB, tB);
        }
    }

    const float a = prelu[0];
    #pragma unroll
    for (int j = 0; j < 4; ++j) {
        const float v = acc[j];
        out[((z0 + j) << 14) + (y << 7) + x] = (v >= 0.0f) ? v : a * v;
    }
}

// ---------------------------------------------------------------------------
extern "C" void kernel_launch(void* const* d_in, const int* in_sizes, int n_in,
                              void* d_out, int out_size, void* d_ws, size_t ws_size,
                              hipStream_t stream) {
    const float* sino  = (const float*)d_in[0];   // (1,1,96,96,192)
    const float* wgt   = (const float*)d_in[1];   // (1,96,96,192)
    const float* prelu = (const float*)d_in[2];   // (1,)
    float* out = (float*)d_out;                   // 128^3 floats

    const size_t quad_bytes   = (size_t)NPROJ * NPIX * 16;     // 25.17 MB
    const size_t derivq_bytes = (size_t)NPROJ * SLICE * 8;     // 14.16 MB
    const size_t derivp_bytes = (size_t)NPROJ * SLICE * 4;     //  7.08 MB

    unsigned* wq_dw = (unsigned*)d_ws;
    char*     dptr  = (char*)d_ws + quad_bytes;

    if (ws_size >= quad_bytes + derivq_bytes) {
        // primary: shared x-pair loads from overlapping derivq
        k_deriv2<<<dim3(NPROJ * NANG), dim3(192), 0, stream>>>(sino, wgt, (uint2*)dptr);
        k_bp2d_pair<<<dim3(NPROJ, 32), dim3(256), 0, stream>>>((const uint2*)dptr, wq_dw);
    } else {
        // fallback: r13 path (per-pixel dword loads)
        k_deriv<<<dim3(NPROJ * NANG), dim3(192), 0, stream>>>(sino, wgt, (unsigned*)dptr);
        k_bp2d_fb<<<dim3(NPROJ, 32), dim3(256), 0, stream>>>((const unsigned*)dptr, wq_dw);
    }
    k_bp3d_q<<<dim3(64, 32), dim3(256), 0, stream>>>((const uint4*)wq_dw, prelu, out);
}